// Round 8
// baseline (31.610 us; speedup 1.0000x reference)
//
#include <hip/hip_runtime.h>
#include <hip/hip_bf16.h>

#define SCALE_F 173.71779276130078f   // 400 / ln(10)
#define BLOCK 256
#define TILES 8                       // 32-token MFMA tiles per wave (256 tok/wave)

typedef __attribute__((ext_vector_type(8)))  __bf16 bf16x8;
typedef __attribute__((ext_vector_type(16))) float  f32x16;

union FragU { unsigned u[4]; bf16x8 v; };

__device__ inline unsigned pk_bf16(float lo, float hi) {   // RNE pack: lo->bits[15:0], hi->bits[31:16]
    unsigned r;
    asm("v_cvt_pk_bf16_f32 %0, %1, %2" : "=v"(r) : "v"(lo), "v"(hi));
    return r;
}

__global__ void zero_ws_kernel(float* __restrict__ ws, int n) {
    int i = blockIdx.x * 256 + threadIdx.x;
    if (i < n) ws[i] = 0.0f;
}

__global__ __launch_bounds__(BLOCK, 4) void strength_mfma_kernel(
    const float* __restrict__ x,    // [N][6]
    const float* __restrict__ W1,   // [6][32]
    const float* __restrict__ b1,   // [32]
    const float* __restrict__ wr,   // [32]
    const float* __restrict__ brp,  // scalar
    const float* __restrict__ wz,   // [32]
    const float* __restrict__ bzp,  // scalar
    const int*   __restrict__ seg,  // [N] sorted
    int N,
    float* __restrict__ num,        // [G]
    float* __restrict__ den)        // [G]
{
    const int  tid  = threadIdx.x;
    const int  lane = tid & 63;
    const int  l32  = lane & 31;
    const bool lo   = (lane < 32);

    const int wv    = blockIdx.x * (BLOCK / 64) + (tid >> 6);
    const int wbase = wv * (32 * TILES);          // 256 tokens per wave
    if (wbase >= N) return;
    const int tbase = wbase + l32 * TILES;        // this lane's 8 consecutive tokens

    // ---- A-operand: W1^T with bias folded at k=6 (lanes>=32 hold k=8..15 = 0) ----
    FragU A;
    {
        float w0=0.f,w1=0.f,w2=0.f,w3=0.f,w4=0.f,w5=0.f,bb=0.f;
        if (lo) {
            w0 = W1[0*32+l32]; w1 = W1[1*32+l32]; w2 = W1[2*32+l32];
            w3 = W1[3*32+l32]; w4 = W1[4*32+l32]; w5 = W1[5*32+l32];
            bb = b1[l32];
        }
        A.u[0] = pk_bf16(w0, w1);
        A.u[1] = pk_bf16(w2, w3);
        A.u[2] = pk_bf16(w4, w5);
        A.u[3] = pk_bf16(bb, 0.f);                // k6 = bias, k7 = 0
    }

    // ---- layer-2 weights aligned to the C/D row layout:
    //      row(q) = (q&3) + 8*(q>>2) + 4*(lane>>5) ----
    float wrv[16], wzv[16];
    {
        const int rb = (lane >> 5) * 4;
        #pragma unroll
        for (int q = 0; q < 16; ++q) {
            int row = (q & 3) + 8 * (q >> 2) + rb;
            wrv[q] = wr[row];
            wzv[q] = wz[row];
        }
    }

    // ---- segment ids for this lane's 8 tokens ----
    int sgid[8];
    if (tbase + 8 <= N) {
        int4 sa = *(const int4*)(seg + tbase);
        int4 sb = *(const int4*)(seg + tbase + 4);
        sgid[0]=sa.x; sgid[1]=sa.y; sgid[2]=sa.z; sgid[3]=sa.w;
        sgid[4]=sb.x; sgid[5]=sb.y; sgid[6]=sb.z; sgid[7]=sb.w;
    } else {
        #pragma unroll
        for (int t = 0; t < 8; ++t)
            sgid[t] = (tbase + t < N) ? seg[tbase + t] : -1;
    }

    const float brv = *brp;
    const float bzv = *bzp;

    int   key = -1;
    float E = 0.f, ER = 0.f;

    #pragma unroll 2
    for (int t = 0; t < TILES; ++t) {
        const int  token = tbase + t;
        const bool ok    = lo && (token < N);

        // ---- B-operand: token features (k0..5), 1.0 at k6; zero elsewhere ----
        float2 p0 = {0.f,0.f}, p1 = {0.f,0.f}, p2 = {0.f,0.f};
        if (ok) {
            const float* xp = x + (size_t)token * 6;
            p0 = *(const float2*)(xp + 0);
            p1 = *(const float2*)(xp + 2);
            p2 = *(const float2*)(xp + 4);
        }
        FragU B;
        B.u[0] = pk_bf16(p0.x, p0.y);
        B.u[1] = pk_bf16(p1.x, p1.y);
        B.u[2] = pk_bf16(p2.x, p2.y);
        B.u[3] = ok ? 0x00003F80u : 0u;           // bf16 1.0 at k6

        // ---- layer 1 on the matrix core: H[32 hid][32 tok] ----
        f32x16 acc = {0.f,0.f,0.f,0.f,0.f,0.f,0.f,0.f,
                      0.f,0.f,0.f,0.f,0.f,0.f,0.f,0.f};
        acc = __builtin_amdgcn_mfma_f32_32x32x16_bf16(A.v, B.v, acc, 0, 0, 0);

        // ---- layer 2 in fp32: each lane covers 16 of 32 hiddens for token l32 ----
        float rp = 0.f, zp = 0.f;
        #pragma unroll
        for (int q = 0; q < 16; ++q) {
            float h = fmaxf(acc[q], 0.f);         // ReLU
            rp = fmaf(h, wrv[q], rp);
            zp = fmaf(h, wzv[q], zp);
        }
        rp += __shfl_xor(rp, 32);                 // combine the two hidden-halves
        zp += __shfl_xor(zp, 32);

        if (ok) {
            float rt = rp + brv;
            float e  = __expf(zp + bzv);          // no max-shift: ratio invariant
            int   s  = sgid[t];
            if (s != key) {
                if (key >= 0) { atomicAdd(&den[key], E); atomicAdd(&num[key], ER); }
                key = s; E = 0.f; ER = 0.f;
            }
            E += e; ER = fmaf(e, rt, ER);
        }
    }

    // ---- full-wave segmented scan over lane tails (hi lanes: key=-1, E=0) ----
    #pragma unroll
    for (int d = 1; d < 64; d <<= 1) {
        int   k2 = __shfl_up(key, d);
        float E2 = __shfl_up(E,   d);
        float R2 = __shfl_up(ER,  d);
        if (lane >= d && k2 == key) { E += E2; ER += R2; }
    }
    int  knext = __shfl_down(key, 1);
    bool last  = (lane == 63) || (knext != key);
    if (last && key >= 0) {
        atomicAdd(&den[key], E);
        atomicAdd(&num[key], ER);
    }
}

__global__ void finalize_kernel(const float* __restrict__ num,
                                const float* __restrict__ den,
                                float* __restrict__ out, int G) {
    int g = blockIdx.x * 256 + threadIdx.x;
    if (g < G) {
        float d = den[g];
        out[g] = (d > 0.0f) ? (SCALE_F * num[g] / d) : 0.0f;
    }
}

extern "C" void kernel_launch(void* const* d_in, const int* in_sizes, int n_in,
                              void* d_out, int out_size, void* d_ws, size_t ws_size,
                              hipStream_t stream) {
    const float* x   = (const float*)d_in[0];
    const float* W1  = (const float*)d_in[1];
    const float* b1  = (const float*)d_in[2];
    const float* wr  = (const float*)d_in[3];
    const float* br  = (const float*)d_in[4];
    const float* wz  = (const float*)d_in[5];
    const float* bz  = (const float*)d_in[6];
    const int*   seg = (const int*)d_in[7];

    int N = in_sizes[7];     // 2097152
    int G = out_size;        // 8192

    float* num = (float*)d_ws;
    float* den = num + G;
    float* out = (float*)d_out;

    int zn = 2 * G;
    zero_ws_kernel<<<(zn + 255) / 256, 256, 0, stream>>>(num, zn);

    long tokens_per_block = (long)(BLOCK / 64) * 32 * TILES;   // 1024
    int  nblocks = (int)(((long)N + tokens_per_block - 1) / tokens_per_block);
    strength_mfma_kernel<<<nblocks, BLOCK, 0, stream>>>(
        x, W1, b1, wr, br, wz, bz, seg, N, num, den);

    finalize_kernel<<<(G + 255) / 256, 256, 0, stream>>>(num, den, out, G);
}

// Round 9
// 28.694 us; speedup vs baseline: 1.1016x; 1.1016x over previous
//
#include <hip/hip_runtime.h>

#define SCALE_F 173.71779276130078f   // 400 / ln(10)
#define BLOCK 256
#define TPT 4                         // consecutive tokens per thread

typedef float v2f __attribute__((ext_vector_type(2)));

__global__ void zero_ws_kernel(float* __restrict__ ws, int n) {
    int i = blockIdx.x * 256 + threadIdx.x;
    if (i < n) ws[i] = 0.0f;
}

__global__ __launch_bounds__(BLOCK, 8) void strength_main_kernel(
    const float* __restrict__ x,    // [N][6]
    const float* __restrict__ W1,   // [6][32]
    const float* __restrict__ b1,   // [32]
    const float* __restrict__ wr,   // [32]
    const float* __restrict__ brp,  // scalar
    const float* __restrict__ wz,   // [32]
    const float* __restrict__ bzp,  // scalar
    const int*   __restrict__ seg,  // [N] sorted
    int N,
    float* __restrict__ num,        // [G]
    float* __restrict__ den)        // [G]
{
    const int tid  = threadIdx.x;
    const int lane = tid & 63;

    const int t0   = blockIdx.x * (BLOCK * TPT) + tid * TPT;
    const int kmax = (t0 >= N) ? 0 : ((N - t0 < TPT) ? (N - t0) : TPT);

    // ---- load 4 consecutive tokens (6 float4 = 96B) + 4 seg ids ----
    float a[TPT * 6];
    int   sg[TPT];
    if (kmax == TPT) {
        const float4* xp = (const float4*)(x + (size_t)t0 * 6);
        #pragma unroll
        for (int i = 0; i < 6; ++i) {
            float4 v = xp[i];
            a[4 * i + 0] = v.x; a[4 * i + 1] = v.y;
            a[4 * i + 2] = v.z; a[4 * i + 3] = v.w;
        }
        int4 s0v = *(const int4*)(seg + t0);
        sg[0] = s0v.x; sg[1] = s0v.y; sg[2] = s0v.z; sg[3] = s0v.w;
    } else {
        #pragma unroll
        for (int k = 0; k < TPT; ++k) {
            if (k < kmax) {
                const float* xp = x + (size_t)(t0 + k) * 6;
                #pragma unroll
                for (int i = 0; i < 6; ++i) a[k * 6 + i] = xp[i];
                sg[k] = seg[t0 + k];
            } else {
                #pragma unroll
                for (int i = 0; i < 6; ++i) a[k * 6 + i] = 0.0f;
                sg[k] = -1;
            }
        }
    }

    // ---- repack into token-pair v2f: X[p][f] = {tok(2p).f, tok(2p+1).f} ----
    v2f X[2][6];
    #pragma unroll
    for (int p = 0; p < 2; ++p)
        #pragma unroll
        for (int f = 0; f < 6; ++f)
            X[p][f] = (v2f){ a[(2*p)*6 + f], a[(2*p+1)*6 + f] };

    const float brv = *brp;   // uniform -> s_load
    const float bzv = *bzp;

    v2f R[2], Z[2];
    R[0] = (v2f){brv, brv}; R[1] = (v2f){brv, brv};
    Z[0] = (v2f){bzv, bzv}; Z[1] = (v2f){bzv, bzv};

    // ---- MLP: 16 col-pairs, tokens processed 2-wide via v_pk_fma_f32.
    //      Weights are wave-uniform global derefs -> s_load (SGPRs). ----
    #pragma unroll 2
    for (int c = 0; c < 16; ++c) {
        const float2 w0 = *(const float2*)&W1[0 * 32 + 2 * c];
        const float2 w1 = *(const float2*)&W1[1 * 32 + 2 * c];
        const float2 w2 = *(const float2*)&W1[2 * 32 + 2 * c];
        const float2 w3 = *(const float2*)&W1[3 * 32 + 2 * c];
        const float2 w4 = *(const float2*)&W1[4 * 32 + 2 * c];
        const float2 w5 = *(const float2*)&W1[5 * 32 + 2 * c];
        const float2 bb = *(const float2*)&b1[2 * c];
        const float2 rr = *(const float2*)&wr[2 * c];
        const float2 zz = *(const float2*)&wz[2 * c];

        #pragma unroll
        for (int j = 0; j < 2; ++j) {   // the two columns of this pair
            const float wj0 = j ? w0.y : w0.x;
            const float wj1 = j ? w1.y : w1.x;
            const float wj2 = j ? w2.y : w2.x;
            const float wj3 = j ? w3.y : w3.x;
            const float wj4 = j ? w4.y : w4.x;
            const float wj5 = j ? w5.y : w5.x;
            const float bbj = j ? bb.y : bb.x;
            const float rrj = j ? rr.y : rr.x;
            const float zzj = j ? zz.y : zz.x;
            const v2f vw0 = (v2f){wj0, wj0}, vw1 = (v2f){wj1, wj1};
            const v2f vw2 = (v2f){wj2, wj2}, vw3 = (v2f){wj3, wj3};
            const v2f vw4 = (v2f){wj4, wj4}, vw5 = (v2f){wj5, wj5};
            const v2f vbb = (v2f){bbj, bbj};
            const v2f vrr = (v2f){rrj, rrj}, vzz = (v2f){zzj, zzj};
            #pragma unroll
            for (int p = 0; p < 2; ++p) {
                v2f h = X[p][0]*vw0 + (X[p][1]*vw1 + (X[p][2]*vw2 +
                        (X[p][3]*vw3 + (X[p][4]*vw4 + (X[p][5]*vw5 + vbb)))));
                h = __builtin_elementwise_max(h, (v2f){0.f, 0.f});   // v_pk_max_f32
                R[p] = h * vrr + R[p];
                Z[p] = h * vzz + Z[p];
            }
        }
    }

    // ---- unpack per-token r,z ----
    float rv[TPT] = { R[0].x, R[0].y, R[1].x, R[1].y };
    float zv[TPT] = { Z[0].x, Z[0].y, Z[1].x, Z[1].y };

    // ---- per-thread serial run accumulation; interior boundaries flush
    //      straight to global (adds commute -> correct) ----
    int   key = (kmax > 0) ? sg[0] : -1;
    float E = 0.0f, ER = 0.0f;
    #pragma unroll
    for (int k = 0; k < TPT; ++k) {
        if (k < kmax) {
            float e = __expf(zv[k]);       // no max-shift: ratio invariant
            if (sg[k] != key) {            // rare (~1.5% of threads)
                atomicAdd(&den[key], E);
                atomicAdd(&num[key], ER);
                key = sg[k]; E = 0.0f; ER = 0.0f;
            }
            E += e; ER = fmaf(e, rv[k], ER);
        }
    }

    // ---- one segmented inclusive scan per wave over lane tails ----
    #pragma unroll
    for (int d = 1; d < 64; d <<= 1) {
        int   k2 = __shfl_up(key, d);
        float E2 = __shfl_up(E,   d);
        float R2 = __shfl_up(ER,  d);
        if (lane >= d && k2 == key) { E += E2; ER += R2; }
    }
    int knext = __shfl_down(key, 1);
    bool last = (lane == 63) || (knext != key);
    if (last && key >= 0) {
        atomicAdd(&den[key], E);
        atomicAdd(&num[key], ER);
    }
}

__global__ void finalize_kernel(const float* __restrict__ num,
                                const float* __restrict__ den,
                                float* __restrict__ out, int G) {
    int g = blockIdx.x * 256 + threadIdx.x;
    if (g < G) {
        float d = den[g];
        out[g] = (d > 0.0f) ? (SCALE_F * num[g] / d) : 0.0f;
    }
}

extern "C" void kernel_launch(void* const* d_in, const int* in_sizes, int n_in,
                              void* d_out, int out_size, void* d_ws, size_t ws_size,
                              hipStream_t stream) {
    const float* x   = (const float*)d_in[0];
    const float* W1  = (const float*)d_in[1];
    const float* b1  = (const float*)d_in[2];
    const float* wr  = (const float*)d_in[3];
    const float* br  = (const float*)d_in[4];
    const float* wz  = (const float*)d_in[5];
    const float* bz  = (const float*)d_in[6];
    const int*   seg = (const int*)d_in[7];

    int N = in_sizes[7];     // 2097152
    int G = out_size;        // 8192

    float* num = (float*)d_ws;
    float* den = num + G;
    float* out = (float*)d_out;

    int zn = 2 * G;
    zero_ws_kernel<<<(zn + 255) / 256, 256, 0, stream>>>(num, zn);

    long tokens_per_block = (long)BLOCK * TPT;   // 1024
    int  nblocks = (int)(((long)N + tokens_per_block - 1) / tokens_per_block);
    strength_main_kernel<<<nblocks, BLOCK, 0, stream>>>(
        x, W1, b1, wr, br, wz, bz, seg, N, num, den);

    finalize_kernel<<<(G + 255) / 256, 256, 0, stream>>>(num, den, out, G);
}